// Round 15
// baseline (142.288 us; speedup 1.0000x reference)
//
#include <hip/hip_runtime.h>
#include <hip/hip_bf16.h>

#define N_NODES 50000
#define N_EDGES 800000
#define NBKT ((N_NODES + 127) / 128)        // 391 coarse buckets (128 dst each)
#define BCAP 4096                           // fixed bucket capacity (mean 2048)
#define NB_B1 ((N_EDGES + 4095) / 4096)     // 196 bucket1 blocks
#define NB_GEMM1 ((N_NODES + 63) / 64)      // 782 gemm blocks

typedef __attribute__((ext_vector_type(8))) short short8;
typedef __attribute__((ext_vector_type(4))) float float4v;

__device__ __forceinline__ unsigned short f2bf(float f) {
    unsigned u = __float_as_uint(f);
    u += 0x7FFF + ((u >> 16) & 1);          // round-to-nearest-even
    return (unsigned short)(u >> 16);
}
__device__ __forceinline__ float bf2f(unsigned short u) {
    return __uint_as_float((unsigned)u << 16);
}
// fp8 e4m3 (OCP) via bit tricks: exp bias 7; f32 carrying trick with 2^±120.
__device__ __forceinline__ unsigned char f2fp8(float v) {
    unsigned b = __float_as_uint(v * 0x1p-120f);
    unsigned s = (b >> 24) & 0x80u;
    unsigned mag = b & 0x7FFFFFFFu;
    mag += 0x7FFFFu + ((mag >> 20) & 1u);   // RNE to 3 mantissa bits
    unsigned code = mag >> 20;
    if (code > 0x7Eu) code = 0x7Eu;         // clamp (never hit at our scales)
    return (unsigned char)(s | code);
}
__device__ __forceinline__ float fp82f(unsigned c) {
    unsigned u = ((c & 0x80u) << 24) | ((c & 0x7Fu) << 20);
    return __uint_as_float(u) * 0x1p+120f;  // handles denormals via f32 denorm
}

// ---------------------------------------------------------------------------
// Prep: Wt1[96][256]=bf16(W1^T); Wt2[64][96]=bf16(W2^T); zero gcnt + pooled.
// ---------------------------------------------------------------------------
__global__ __launch_bounds__(256) void prep_kernel(const float* __restrict__ W1,
                                                   const float* __restrict__ W2,
                                                   unsigned short* __restrict__ Wt1,
                                                   unsigned short* __restrict__ Wt2,
                                                   int* __restrict__ gcnt,
                                                   float* __restrict__ pooled) {
    int i = blockIdx.x * 256 + threadIdx.x;
    if (i < 24576) {                        // 96*256
        int n = i >> 8, k = i & 255;
        Wt1[i] = f2bf(W1[k * 96 + n]);
    } else if (i < 30720) {                 // + 64*96
        int j = i - 24576;
        int n = j / 96, k = j - n * 96;
        Wt2[j] = f2bf(W2[k * 64 + n]);
    } else if (i < 30720 + NBKT) {
        gcnt[i - 30720] = 0;
    } else if (i < 30720 + NBKT + 64) {
        pooled[i - 30720 - NBKT] = 0.f;
    }
}

// ---------------------------------------------------------------------------
// MFMA GEMM body: outb[rows][N] (fp8 e4m3) = src[rows][K] @ Wt[N][K]^T
// BM=64 (4 waves x 16 rows), BK=32, mfma_f32_16x16x32_bf16.
// ---------------------------------------------------------------------------
template <int K, int N, bool IN_BF16>
__device__ __forceinline__ void gemm_body(int bx, const void* __restrict__ src_,
                                          const unsigned short* __restrict__ Wt,
                                          unsigned char* __restrict__ outb,
                                          unsigned short* a_lds,   // [64*40]
                                          unsigned short* b_lds) { // [N*40]
    constexpr int NF = N / 16;
    constexpr int LDA = 40;
    const int tid = threadIdx.x;
    const int lane = tid & 63;
    const int w = tid >> 6;
    const int row0 = bx * 64;
    const int fr = lane & 15;
    const int fk = (lane >> 4) * 8;

    float4v acc[NF];
    #pragma unroll
    for (int nn = 0; nn < NF; ++nn) acc[nn] = (float4v){0.f, 0.f, 0.f, 0.f};

    const int srow = tid >> 2;
    const int sko  = (tid & 3) * 8;

    for (int k0 = 0; k0 < K; k0 += 32) {
        {
            int grow = row0 + srow;
            short8 s = (short8){0, 0, 0, 0, 0, 0, 0, 0};
            if (grow < N_NODES) {
                if constexpr (IN_BF16) {
                    const unsigned short* src = (const unsigned short*)src_;
                    s = *reinterpret_cast<const short8*>(&src[(size_t)grow * K + k0 + sko]);
                } else {
                    const float* src = (const float*)src_;
                    const float4* p = reinterpret_cast<const float4*>(&src[(size_t)grow * K + k0 + sko]);
                    float4 v0 = p[0], v1 = p[1];
                    s[0] = (short)f2bf(v0.x); s[1] = (short)f2bf(v0.y);
                    s[2] = (short)f2bf(v0.z); s[3] = (short)f2bf(v0.w);
                    s[4] = (short)f2bf(v1.x); s[5] = (short)f2bf(v1.y);
                    s[6] = (short)f2bf(v1.z); s[7] = (short)f2bf(v1.w);
                }
            }
            *reinterpret_cast<short8*>(&a_lds[srow * LDA + sko]) = s;
        }
        for (int c = tid; c < N * 4; c += 256) {
            int n = c >> 2, ko = (c & 3) * 8;
            short8 s = *reinterpret_cast<const short8*>(&Wt[(size_t)n * K + k0 + ko]);
            *reinterpret_cast<short8*>(&b_lds[n * LDA + ko]) = s;
        }
        __syncthreads();
        short8 af = *reinterpret_cast<short8*>(&a_lds[(w * 16 + fr) * LDA + fk]);
        #pragma unroll
        for (int nn = 0; nn < NF; ++nn) {
            short8 bf = *reinterpret_cast<short8*>(&b_lds[(nn * 16 + fr) * LDA + fk]);
            acc[nn] = __builtin_amdgcn_mfma_f32_16x16x32_bf16(af, bf, acc[nn], 0, 0, 0);
        }
        __syncthreads();
    }
    const int orow_base = row0 + w * 16 + (lane >> 4) * 4;
    const int ocol = lane & 15;
    #pragma unroll
    for (int nn = 0; nn < NF; ++nn) {
        #pragma unroll
        for (int r = 0; r < 4; ++r) {
            int grow = orow_base + r;
            if (grow < N_NODES) outb[(size_t)grow * N + nn * 16 + ocol] = f2fp8(acc[nn][r]);
        }
    }
}

// ---------------------------------------------------------------------------
// mega1: blocks [0,196) run bucket1; blocks [196, 196+782) run gemm1.
// ---------------------------------------------------------------------------
__global__ __launch_bounds__(256) void mega1_kernel(const int* __restrict__ srcv,
                                                    const int* __restrict__ dstv,
                                                    const float* __restrict__ wv,
                                                    int* __restrict__ gcnt,
                                                    int2* __restrict__ scratch,
                                                    const float* __restrict__ x,
                                                    const unsigned short* __restrict__ Wt1,
                                                    unsigned char* __restrict__ outA) {
    __shared__ int lhist[NBKT];
    __shared__ int gb[NBKT];
    __shared__ unsigned short a_lds[64 * 40];
    __shared__ unsigned short b_lds[96 * 40];
    const int t = threadIdx.x;
    if (blockIdx.x < NB_B1) {
        for (int i = t; i < NBKT; i += 256) lhist[i] = 0;
        __syncthreads();
        const int base = blockIdx.x * 4096;
        int rank[16], bkt[16], dst[16];
        unsigned pay[16];
        #pragma unroll
        for (int i = 0; i < 16; ++i) {
            int e = base + t + i * 256;
            if (e < N_EDGES) {
                int d = dstv[e];
                dst[i] = d;
                bkt[i] = d >> 7;
                unsigned w15 = __float2uint_rn(wv[e] * 32768.0f);
                if (w15 > 32767u) w15 = 32767u;
                pay[i] = ((unsigned)srcv[e] << 15) | w15;
                rank[i] = atomicAdd(&lhist[bkt[i]], 1);
            } else {
                bkt[i] = -1;
            }
        }
        __syncthreads();
        for (int b = t; b < NBKT; b += 256) {
            int c = lhist[b];
            gb[b] = (c > 0) ? atomicAdd(&gcnt[b], c) : 0;
        }
        __syncthreads();
        #pragma unroll
        for (int i = 0; i < 16; ++i) {
            if (bkt[i] >= 0) {
                int pos = gb[bkt[i]] + rank[i];
                if (pos < BCAP)
                    scratch[(size_t)bkt[i] * BCAP + pos] = make_int2(dst[i], (int)pay[i]);
            }
        }
    } else {
        gemm_body<256, 96, false>(blockIdx.x - NB_B1, x, Wt1, outA, a_lds, b_lds);
    }
}

// ---------------------------------------------------------------------------
// GEMM2 standalone: h1(bf16) @ W2 -> fp8 support2
// ---------------------------------------------------------------------------
__global__ __launch_bounds__(256) void gemm2_kernel(const unsigned short* __restrict__ h1,
                                                    const unsigned short* __restrict__ Wt2,
                                                    unsigned char* __restrict__ outA) {
    __shared__ unsigned short a_lds[64 * 40];
    __shared__ unsigned short b_lds[64 * 40];
    gemm_body<96, 64, true>(blockIdx.x, h1, Wt2, outA, a_lds, b_lds);
}

// ---------------------------------------------------------------------------
// Sort pass 2: one block per bucket; base self-computed from gcnt prefix.
// ---------------------------------------------------------------------------
__global__ __launch_bounds__(256) void bucket2_kernel(const int2* __restrict__ scratch,
                                                      const int* __restrict__ gcnt,
                                                      int* __restrict__ off,
                                                      unsigned* __restrict__ ewq) {
    __shared__ int dh[128];
    __shared__ int sx[128];
    __shared__ int dcur[128];
    __shared__ int redsum[256];
    const int t = threadIdx.x;
    const int b = blockIdx.x;
    const int d0 = b << 7;
    const int cnt = min(gcnt[b], BCAP);
    const size_t sbase = (size_t)b * BCAP;
    int pre = 0;
    for (int i = t; i < b; i += 256) pre += min(gcnt[i], BCAP);
    redsum[t] = pre;
    __syncthreads();
    #pragma unroll
    for (int d = 128; d > 0; d >>= 1) {
        if (t < d) redsum[t] += redsum[t + d];
        __syncthreads();
    }
    const int obase = redsum[0];
    if (t == 0 && b == NBKT - 1) off[N_NODES] = obase + cnt;
    if (t < 128) dh[t] = 0;
    __syncthreads();
    for (int i = t; i < cnt; i += 256)
        atomicAdd(&dh[scratch[sbase + i].x & 127], 1);
    __syncthreads();
    int myc = (t < 128) ? dh[t] : 0;
    if (t < 128) sx[t] = myc;
    __syncthreads();
    #pragma unroll
    for (int d = 1; d < 128; d <<= 1) {
        int u = (t < 128 && t >= d) ? sx[t - d] : 0;
        __syncthreads();
        if (t < 128) sx[t] += u;
        __syncthreads();
    }
    if (t < 128) {
        int excl = obase + sx[t] - myc;
        dcur[t] = excl;
        if (d0 + t < N_NODES) off[d0 + t] = excl;
    }
    __syncthreads();
    for (int i = t; i < cnt; i += 256) {
        int2 e = scratch[sbase + i];
        int pos = atomicAdd(&dcur[e.x & 127], 1);
        ewq[pos] = (unsigned)e.y;
    }
}

// ---------------------------------------------------------------------------
// Gather aggregation (fp8 table, packed 4B edges), 8x MLP, edge-split x2:
// 2 threads per (node, quad) — thread `half` sums its half of the edge range
// (one 8-deep latency round for mean degree 16), then pairs combine via
// __shfl_xor(.,1). Pairs are tid {2k,2k+1} -> always same wave.
// ---------------------------------------------------------------------------
template <int DIM>
__global__ __launch_bounds__(256) void gather_agg_kernel(const unsigned char* __restrict__ sup8,
                                                         const int* __restrict__ off,
                                                         const unsigned* __restrict__ ewq,
                                                         const float* __restrict__ bias,
                                                         unsigned short* __restrict__ outb) {
    const int NQ = DIM / 4;
    const float kInv = 1.0f / 32768.0f;
    unsigned gid = blockIdx.x * 256u + threadIdx.x;
    if (gid >= (unsigned)N_NODES * NQ * 2) return;
    unsigned n = gid / (NQ * 2);
    unsigned rem = gid - n * (NQ * 2);
    unsigned q = rem >> 1;
    unsigned half = rem & 1;
    const int ne0 = off[n], ne1 = off[n + 1];
    const int emid = ne0 + ((ne1 - ne0 + 1) >> 1);
    int e = half ? emid : ne0;
    const int eend = half ? ne1 : emid;
    float4 acc[8];
    #pragma unroll
    for (int i = 0; i < 8; ++i) acc[i] = make_float4(0.f, 0.f, 0.f, 0.f);
    for (; e + 8 <= eend; e += 8) {
        unsigned p[8];
        #pragma unroll
        for (int i = 0; i < 8; ++i) p[i] = ewq[e + i];
        unsigned u[8];
        #pragma unroll
        for (int i = 0; i < 8; ++i)
            u[i] = *reinterpret_cast<const unsigned*>(&sup8[(size_t)(p[i] >> 15) * DIM + q * 4]);
        #pragma unroll
        for (int i = 0; i < 8; ++i) {
            float w = (float)(p[i] & 32767u) * kInv;
            acc[i].x += fp82f(u[i]) * w;
            acc[i].y += fp82f(u[i] >> 8) * w;
            acc[i].z += fp82f(u[i] >> 16) * w;
            acc[i].w += fp82f(u[i] >> 24) * w;
        }
    }
    for (; e < eend; ++e) {
        unsigned p = ewq[e];
        float w = (float)(p & 32767u) * kInv;
        unsigned u = *reinterpret_cast<const unsigned*>(&sup8[(size_t)(p >> 15) * DIM + q * 4]);
        acc[0].x += fp82f(u) * w;
        acc[0].y += fp82f(u >> 8) * w;
        acc[0].z += fp82f(u >> 16) * w;
        acc[0].w += fp82f(u >> 24) * w;
    }
    #pragma unroll
    for (int i = 1; i < 8; ++i) {
        acc[0].x += acc[i].x;
        acc[0].y += acc[i].y;
        acc[0].z += acc[i].z;
        acc[0].w += acc[i].w;
    }
    // pair combine: lane 2k (+half 0) + lane 2k+1 (half 1)
    acc[0].x += __shfl_xor(acc[0].x, 1);
    acc[0].y += __shfl_xor(acc[0].y, 1);
    acc[0].z += __shfl_xor(acc[0].z, 1);
    acc[0].w += __shfl_xor(acc[0].w, 1);
    if (half == 0) {
        const float4 bb = *reinterpret_cast<const float4*>(&bias[q * 4]);
        ushort4 o;
        o.x = f2bf(fmaxf(acc[0].x + bb.x, 0.f));
        o.y = f2bf(fmaxf(acc[0].y + bb.y, 0.f));
        o.z = f2bf(fmaxf(acc[0].z + bb.z, 0.f));
        o.w = f2bf(fmaxf(acc[0].w + bb.w, 0.f));
        *reinterpret_cast<ushort4*>(&outb[(size_t)n * DIM + q * 4]) = o;
    }
}

// ---------------------------------------------------------------------------
// Column-sum of h2 (bf16, already bias+relu'd) over all nodes -> pooled[64]
// ---------------------------------------------------------------------------
__global__ __launch_bounds__(256) void colsum_kernel(const unsigned short* __restrict__ h2,
                                                     float* __restrict__ pooled) {
    __shared__ float red[4][64];
    const int t = threadIdx.x;
    const int c = t & 63, r = t >> 6;
    float s = 0.f;
    const int base = blockIdx.x * 256;
    for (int i = r; i < 256; i += 4) {
        int n = base + i;
        if (n < N_NODES) s += bf2f(h2[(size_t)n * 64 + c]);
    }
    red[r][c] = s;
    __syncthreads();
    if (r == 0) {
        float v = red[0][c] + red[1][c] + red[2][c] + red[3][c];
        unsafeAtomicAdd(&pooled[c], v);
    }
}

// ---------------------------------------------------------------------------
// Final head: selu(pooled/N) + 0.5*(sub_fea @ fc_w^T + fc_b) -> log_softmax
// ---------------------------------------------------------------------------
__global__ void final_kernel(const float* __restrict__ pooled,
                             const float* __restrict__ sub_fea,
                             const float* __restrict__ fc_w,
                             const float* __restrict__ fc_b,
                             float* __restrict__ out) {
    const int c = threadIdx.x;  // 0..63
    float p = pooled[c] * (1.0f / (float)N_NODES);
    const float kScale = 1.0507009873554805f;
    const float kAlpha = 1.6732632423543772f;
    float se = (p > 0.f) ? kScale * p : kScale * kAlpha * (expf(p) - 1.f);
    float xe = fc_b[c];
    for (int k = 0; k < 128; ++k) xe += sub_fea[k] * fc_w[c * 128 + k];
    float v = se + 0.5f * xe;
    float m = v;
    #pragma unroll
    for (int off = 32; off >= 1; off >>= 1) m = fmaxf(m, __shfl_xor(m, off));
    float ex = expf(v - m);
    float ss = ex;
    #pragma unroll
    for (int off = 32; off >= 1; off >>= 1) ss += __shfl_xor(ss, off);
    out[c] = v - m - logf(ss);
}

// ---------------------------------------------------------------------------
extern "C" void kernel_launch(void* const* d_in, const int* in_sizes, int n_in,
                              void* d_out, int out_size, void* d_ws, size_t ws_size,
                              hipStream_t stream) {
    const float* x       = (const float*)d_in[0];
    const int*   ei      = (const int*)d_in[1];   // [2][E]: src row 0, dst row 1
    const float* ew      = (const float*)d_in[2];
    const float* sub_fea = (const float*)d_in[3];
    const float* W1      = (const float*)d_in[4];
    const float* b1      = (const float*)d_in[5];
    const float* W2      = (const float*)d_in[6];
    const float* b2      = (const float*)d_in[7];
    const float* fc_w    = (const float*)d_in[8];
    const float* fc_b    = (const float*)d_in[9];
    float* out = (float*)d_out;

    // Workspace layout (bytes).
    char* base = (char*)d_ws;
    unsigned char* A = (unsigned char*)(base);                  // support fp8, 4.8 MB
    unsigned short* Bb = (unsigned short*)(base + 4800000);     // h1 bf16 (9.6MB) / h2 bf16 (6.4MB)
    float* pooled = (float*)(base + 14400512);                  // 64 f32
    int*   gcnt  = (int*)(base + 14401024);                     // 391 ints
    int*   off   = (int*)(base + 14403072);                     // 50001 ints
    unsigned* ewq = (unsigned*)(base + 14603264);               // 800000 u32 (3.2 MB)
    int2*  scratch = (int2*)(base + 17803264);                  // 391*4096 int2 (12.8 MB)
    unsigned short* Wt1 = (unsigned short*)(base + 30615552);   // 96*256 bf16
    unsigned short* Wt2 = (unsigned short*)(base + 30664704);   // 64*96 bf16

    const int* srcv = ei;
    const int* dstv = ei + N_EDGES;

    // ---- prep (weights + zero counters) ----
    prep_kernel<<<122, 256, 0, stream>>>(W1, W2, Wt1, Wt2, gcnt, pooled);

    // ---- mega1: bucket sort pass 1 || gemm1 (independent) ----
    mega1_kernel<<<NB_B1 + NB_GEMM1, 256, 0, stream>>>(srcv, dstv, ew, gcnt, scratch,
                                                       x, Wt1, A);

    // ---- bucket2: dst-sort within buckets, writes off + ewq ----
    bucket2_kernel<<<NBKT, 256, 0, stream>>>(scratch, gcnt, off, ewq);

    // ---- Layer 1 gather: h1 = bf16(relu(agg(fp8 support1) + b1)) ----
    {
        unsigned total = (unsigned)N_NODES * 24 * 2;
        gather_agg_kernel<96><<<(total + 255) / 256, 256, 0, stream>>>(
            A, off, ewq, b1, Bb);
    }

    // ---- Layer 2: support2 = fp8(h1 @ W2) ----
    gemm2_kernel<<<NB_GEMM1, 256, 0, stream>>>(Bb, Wt2, A);

    // ---- Layer 2 gather: h2 = bf16 relu(agg(fp8 support2) + b2) ----
    {
        unsigned total = (unsigned)N_NODES * 16 * 2;
        gather_agg_kernel<64><<<(total + 255) / 256, 256, 0, stream>>>(
            A, off, ewq, b2, Bb);
    }

    // ---- Pool + head ----
    colsum_kernel<<<(N_NODES + 255) / 256, 256, 0, stream>>>(Bb, pooled);
    final_kernel<<<1, 64, 0, stream>>>(pooled, sub_fea, fc_w, fc_b, out);
}

// Round 16
// 130.247 us; speedup vs baseline: 1.0925x; 1.0925x over previous
//
#include <hip/hip_runtime.h>
#include <hip/hip_bf16.h>

#define N_NODES 50000
#define N_EDGES 800000
#define NBKT ((N_NODES + 127) / 128)        // 391 coarse buckets (128 dst each)
#define BCAP 4096                           // fixed bucket capacity (mean 2048)
#define NB_B1 ((N_EDGES + 4095) / 4096)     // 196 bucket1 blocks
#define NB_GEMM1 ((N_NODES + 63) / 64)      // 782 gemm blocks

typedef __attribute__((ext_vector_type(8))) short short8;
typedef __attribute__((ext_vector_type(4))) float float4v;

__device__ __forceinline__ unsigned short f2bf(float f) {
    unsigned u = __float_as_uint(f);
    u += 0x7FFF + ((u >> 16) & 1);          // round-to-nearest-even
    return (unsigned short)(u >> 16);
}
__device__ __forceinline__ float bf2f(unsigned short u) {
    return __uint_as_float((unsigned)u << 16);
}
// fp8 e4m3 (OCP) via bit tricks: exp bias 7; f32 carrying trick with 2^±120.
__device__ __forceinline__ unsigned char f2fp8(float v) {
    unsigned b = __float_as_uint(v * 0x1p-120f);
    unsigned s = (b >> 24) & 0x80u;
    unsigned mag = b & 0x7FFFFFFFu;
    mag += 0x7FFFFu + ((mag >> 20) & 1u);   // RNE to 3 mantissa bits
    unsigned code = mag >> 20;
    if (code > 0x7Eu) code = 0x7Eu;         // clamp (never hit at our scales)
    return (unsigned char)(s | code);
}
__device__ __forceinline__ float fp82f(unsigned c) {
    unsigned u = ((c & 0x80u) << 24) | ((c & 0x7Fu) << 20);
    return __uint_as_float(u) * 0x1p+120f;  // handles denormals via f32 denorm
}

// ---------------------------------------------------------------------------
// Prep: Wt1[96][256]=bf16(W1^T); Wt2[64][96]=bf16(W2^T); zero gcnt + pooled.
// ---------------------------------------------------------------------------
__global__ __launch_bounds__(256) void prep_kernel(const float* __restrict__ W1,
                                                   const float* __restrict__ W2,
                                                   unsigned short* __restrict__ Wt1,
                                                   unsigned short* __restrict__ Wt2,
                                                   int* __restrict__ gcnt,
                                                   float* __restrict__ pooled) {
    int i = blockIdx.x * 256 + threadIdx.x;
    if (i < 24576) {                        // 96*256
        int n = i >> 8, k = i & 255;
        Wt1[i] = f2bf(W1[k * 96 + n]);
    } else if (i < 30720) {                 // + 64*96
        int j = i - 24576;
        int n = j / 96, k = j - n * 96;
        Wt2[j] = f2bf(W2[k * 64 + n]);
    } else if (i < 30720 + NBKT) {
        gcnt[i - 30720] = 0;
    } else if (i < 30720 + NBKT + 64) {
        pooled[i - 30720 - NBKT] = 0.f;
    }
}

// ---------------------------------------------------------------------------
// MFMA GEMM body: outb[rows][N] (fp8 e4m3) = src[rows][K] @ Wt[N][K]^T
// BM=64 (4 waves x 16 rows), BK=32, mfma_f32_16x16x32_bf16.
// ---------------------------------------------------------------------------
template <int K, int N, bool IN_BF16>
__device__ __forceinline__ void gemm_body(int bx, const void* __restrict__ src_,
                                          const unsigned short* __restrict__ Wt,
                                          unsigned char* __restrict__ outb,
                                          unsigned short* a_lds,   // [64*40]
                                          unsigned short* b_lds) { // [N*40]
    constexpr int NF = N / 16;
    constexpr int LDA = 40;
    const int tid = threadIdx.x;
    const int lane = tid & 63;
    const int w = tid >> 6;
    const int row0 = bx * 64;
    const int fr = lane & 15;
    const int fk = (lane >> 4) * 8;

    float4v acc[NF];
    #pragma unroll
    for (int nn = 0; nn < NF; ++nn) acc[nn] = (float4v){0.f, 0.f, 0.f, 0.f};

    const int srow = tid >> 2;
    const int sko  = (tid & 3) * 8;

    for (int k0 = 0; k0 < K; k0 += 32) {
        {
            int grow = row0 + srow;
            short8 s = (short8){0, 0, 0, 0, 0, 0, 0, 0};
            if (grow < N_NODES) {
                if constexpr (IN_BF16) {
                    const unsigned short* src = (const unsigned short*)src_;
                    s = *reinterpret_cast<const short8*>(&src[(size_t)grow * K + k0 + sko]);
                } else {
                    const float* src = (const float*)src_;
                    const float4* p = reinterpret_cast<const float4*>(&src[(size_t)grow * K + k0 + sko]);
                    float4 v0 = p[0], v1 = p[1];
                    s[0] = (short)f2bf(v0.x); s[1] = (short)f2bf(v0.y);
                    s[2] = (short)f2bf(v0.z); s[3] = (short)f2bf(v0.w);
                    s[4] = (short)f2bf(v1.x); s[5] = (short)f2bf(v1.y);
                    s[6] = (short)f2bf(v1.z); s[7] = (short)f2bf(v1.w);
                }
            }
            *reinterpret_cast<short8*>(&a_lds[srow * LDA + sko]) = s;
        }
        for (int c = tid; c < N * 4; c += 256) {
            int n = c >> 2, ko = (c & 3) * 8;
            short8 s = *reinterpret_cast<const short8*>(&Wt[(size_t)n * K + k0 + ko]);
            *reinterpret_cast<short8*>(&b_lds[n * LDA + ko]) = s;
        }
        __syncthreads();
        short8 af = *reinterpret_cast<short8*>(&a_lds[(w * 16 + fr) * LDA + fk]);
        #pragma unroll
        for (int nn = 0; nn < NF; ++nn) {
            short8 bf = *reinterpret_cast<short8*>(&b_lds[(nn * 16 + fr) * LDA + fk]);
            acc[nn] = __builtin_amdgcn_mfma_f32_16x16x32_bf16(af, bf, acc[nn], 0, 0, 0);
        }
        __syncthreads();
    }
    const int orow_base = row0 + w * 16 + (lane >> 4) * 4;
    const int ocol = lane & 15;
    #pragma unroll
    for (int nn = 0; nn < NF; ++nn) {
        #pragma unroll
        for (int r = 0; r < 4; ++r) {
            int grow = orow_base + r;
            if (grow < N_NODES) outb[(size_t)grow * N + nn * 16 + ocol] = f2fp8(acc[nn][r]);
        }
    }
}

// ---------------------------------------------------------------------------
// mega1: blocks [0,196) run bucket1; blocks [196, 196+782) run gemm1.
// ---------------------------------------------------------------------------
__global__ __launch_bounds__(256) void mega1_kernel(const int* __restrict__ srcv,
                                                    const int* __restrict__ dstv,
                                                    const float* __restrict__ wv,
                                                    int* __restrict__ gcnt,
                                                    int2* __restrict__ scratch,
                                                    const float* __restrict__ x,
                                                    const unsigned short* __restrict__ Wt1,
                                                    unsigned char* __restrict__ outA) {
    __shared__ int lhist[NBKT];
    __shared__ int gb[NBKT];
    __shared__ unsigned short a_lds[64 * 40];
    __shared__ unsigned short b_lds[96 * 40];
    const int t = threadIdx.x;
    if (blockIdx.x < NB_B1) {
        for (int i = t; i < NBKT; i += 256) lhist[i] = 0;
        __syncthreads();
        const int base = blockIdx.x * 4096;
        int rank[16], bkt[16], dst[16];
        unsigned pay[16];
        #pragma unroll
        for (int i = 0; i < 16; ++i) {
            int e = base + t + i * 256;
            if (e < N_EDGES) {
                int d = dstv[e];
                dst[i] = d;
                bkt[i] = d >> 7;
                unsigned w15 = __float2uint_rn(wv[e] * 32768.0f);
                if (w15 > 32767u) w15 = 32767u;
                pay[i] = ((unsigned)srcv[e] << 15) | w15;
                rank[i] = atomicAdd(&lhist[bkt[i]], 1);
            } else {
                bkt[i] = -1;
            }
        }
        __syncthreads();
        for (int b = t; b < NBKT; b += 256) {
            int c = lhist[b];
            gb[b] = (c > 0) ? atomicAdd(&gcnt[b], c) : 0;
        }
        __syncthreads();
        #pragma unroll
        for (int i = 0; i < 16; ++i) {
            if (bkt[i] >= 0) {
                int pos = gb[bkt[i]] + rank[i];
                if (pos < BCAP)
                    scratch[(size_t)bkt[i] * BCAP + pos] = make_int2(dst[i], (int)pay[i]);
            }
        }
    } else {
        gemm_body<256, 96, false>(blockIdx.x - NB_B1, x, Wt1, outA, a_lds, b_lds);
    }
}

// ---------------------------------------------------------------------------
// GEMM2 standalone: h1(bf16) @ W2 -> fp8 support2
// ---------------------------------------------------------------------------
__global__ __launch_bounds__(256) void gemm2_kernel(const unsigned short* __restrict__ h1,
                                                    const unsigned short* __restrict__ Wt2,
                                                    unsigned char* __restrict__ outA) {
    __shared__ unsigned short a_lds[64 * 40];
    __shared__ unsigned short b_lds[64 * 40];
    gemm_body<96, 64, true>(blockIdx.x, h1, Wt2, outA, a_lds, b_lds);
}

// ---------------------------------------------------------------------------
// Sort pass 2: one block per bucket; base self-computed from gcnt prefix.
// ---------------------------------------------------------------------------
__global__ __launch_bounds__(256) void bucket2_kernel(const int2* __restrict__ scratch,
                                                      const int* __restrict__ gcnt,
                                                      int* __restrict__ off,
                                                      unsigned* __restrict__ ewq) {
    __shared__ int dh[128];
    __shared__ int sx[128];
    __shared__ int dcur[128];
    __shared__ int redsum[256];
    const int t = threadIdx.x;
    const int b = blockIdx.x;
    const int d0 = b << 7;
    const int cnt = min(gcnt[b], BCAP);
    const size_t sbase = (size_t)b * BCAP;
    int pre = 0;
    for (int i = t; i < b; i += 256) pre += min(gcnt[i], BCAP);
    redsum[t] = pre;
    __syncthreads();
    #pragma unroll
    for (int d = 128; d > 0; d >>= 1) {
        if (t < d) redsum[t] += redsum[t + d];
        __syncthreads();
    }
    const int obase = redsum[0];
    if (t == 0 && b == NBKT - 1) off[N_NODES] = obase + cnt;
    if (t < 128) dh[t] = 0;
    __syncthreads();
    for (int i = t; i < cnt; i += 256)
        atomicAdd(&dh[scratch[sbase + i].x & 127], 1);
    __syncthreads();
    int myc = (t < 128) ? dh[t] : 0;
    if (t < 128) sx[t] = myc;
    __syncthreads();
    #pragma unroll
    for (int d = 1; d < 128; d <<= 1) {
        int u = (t < 128 && t >= d) ? sx[t - d] : 0;
        __syncthreads();
        if (t < 128) sx[t] += u;
        __syncthreads();
    }
    if (t < 128) {
        int excl = obase + sx[t] - myc;
        dcur[t] = excl;
        if (d0 + t < N_NODES) off[d0 + t] = excl;
    }
    __syncthreads();
    for (int i = t; i < cnt; i += 256) {
        int2 e = scratch[sbase + i];
        int pos = atomicAdd(&dcur[e.x & 127], 1);
        ewq[pos] = (unsigned)e.y;
    }
}

// ---------------------------------------------------------------------------
// Gather aggregation (fp8 support table, packed 4B edges), 8x MLP (R12 form).
// ---------------------------------------------------------------------------
template <int DIM>
__global__ __launch_bounds__(256) void gather_agg_kernel(const unsigned char* __restrict__ sup8,
                                                         const int* __restrict__ off,
                                                         const unsigned* __restrict__ ewq,
                                                         const float* __restrict__ bias,
                                                         unsigned short* __restrict__ outb) {
    const int NQ = DIM / 4;
    const float kInv = 1.0f / 32768.0f;
    unsigned gid = blockIdx.x * 256u + threadIdx.x;
    if (gid >= (unsigned)N_NODES * NQ) return;
    unsigned n = gid / NQ;
    unsigned q = gid - n * NQ;
    const int e0 = off[n], e1 = off[n + 1];
    float4 acc[8];
    #pragma unroll
    for (int i = 0; i < 8; ++i) acc[i] = make_float4(0.f, 0.f, 0.f, 0.f);
    int e = e0;
    for (; e + 8 <= e1; e += 8) {
        unsigned p[8];
        #pragma unroll
        for (int i = 0; i < 8; ++i) p[i] = ewq[e + i];
        unsigned u[8];
        #pragma unroll
        for (int i = 0; i < 8; ++i)
            u[i] = *reinterpret_cast<const unsigned*>(&sup8[(size_t)(p[i] >> 15) * DIM + q * 4]);
        #pragma unroll
        for (int i = 0; i < 8; ++i) {
            float w = (float)(p[i] & 32767u) * kInv;
            acc[i].x += fp82f(u[i]) * w;
            acc[i].y += fp82f(u[i] >> 8) * w;
            acc[i].z += fp82f(u[i] >> 16) * w;
            acc[i].w += fp82f(u[i] >> 24) * w;
        }
    }
    for (; e < e1; ++e) {
        unsigned p = ewq[e];
        float w = (float)(p & 32767u) * kInv;
        unsigned u = *reinterpret_cast<const unsigned*>(&sup8[(size_t)(p >> 15) * DIM + q * 4]);
        acc[0].x += fp82f(u) * w;
        acc[0].y += fp82f(u >> 8) * w;
        acc[0].z += fp82f(u >> 16) * w;
        acc[0].w += fp82f(u >> 24) * w;
    }
    #pragma unroll
    for (int i = 1; i < 8; ++i) {
        acc[0].x += acc[i].x;
        acc[0].y += acc[i].y;
        acc[0].z += acc[i].z;
        acc[0].w += acc[i].w;
    }
    const float4 bb = *reinterpret_cast<const float4*>(&bias[q * 4]);
    ushort4 o;
    o.x = f2bf(fmaxf(acc[0].x + bb.x, 0.f));
    o.y = f2bf(fmaxf(acc[0].y + bb.y, 0.f));
    o.z = f2bf(fmaxf(acc[0].z + bb.z, 0.f));
    o.w = f2bf(fmaxf(acc[0].w + bb.w, 0.f));
    *reinterpret_cast<ushort4*>(&outb[(size_t)n * DIM + q * 4]) = o;
}

// ---------------------------------------------------------------------------
// Column-sum of h2 (bf16, already bias+relu'd) over all nodes -> pooled[64]
// ---------------------------------------------------------------------------
__global__ __launch_bounds__(256) void colsum_kernel(const unsigned short* __restrict__ h2,
                                                     float* __restrict__ pooled) {
    __shared__ float red[4][64];
    const int t = threadIdx.x;
    const int c = t & 63, r = t >> 6;
    float s = 0.f;
    const int base = blockIdx.x * 256;
    for (int i = r; i < 256; i += 4) {
        int n = base + i;
        if (n < N_NODES) s += bf2f(h2[(size_t)n * 64 + c]);
    }
    red[r][c] = s;
    __syncthreads();
    if (r == 0) {
        float v = red[0][c] + red[1][c] + red[2][c] + red[3][c];
        unsafeAtomicAdd(&pooled[c], v);
    }
}

// ---------------------------------------------------------------------------
// Final head: selu(pooled/N) + 0.5*(sub_fea @ fc_w^T + fc_b) -> log_softmax
// ---------------------------------------------------------------------------
__global__ void final_kernel(const float* __restrict__ pooled,
                             const float* __restrict__ sub_fea,
                             const float* __restrict__ fc_w,
                             const float* __restrict__ fc_b,
                             float* __restrict__ out) {
    const int c = threadIdx.x;  // 0..63
    float p = pooled[c] * (1.0f / (float)N_NODES);
    const float kScale = 1.0507009873554805f;
    const float kAlpha = 1.6732632423543772f;
    float se = (p > 0.f) ? kScale * p : kScale * kAlpha * (expf(p) - 1.f);
    float xe = fc_b[c];
    for (int k = 0; k < 128; ++k) xe += sub_fea[k] * fc_w[c * 128 + k];
    float v = se + 0.5f * xe;
    float m = v;
    #pragma unroll
    for (int off = 32; off >= 1; off >>= 1) m = fmaxf(m, __shfl_xor(m, off));
    float ex = expf(v - m);
    float ss = ex;
    #pragma unroll
    for (int off = 32; off >= 1; off >>= 1) ss += __shfl_xor(ss, off);
    out[c] = v - m - logf(ss);
}

// ---------------------------------------------------------------------------
extern "C" void kernel_launch(void* const* d_in, const int* in_sizes, int n_in,
                              void* d_out, int out_size, void* d_ws, size_t ws_size,
                              hipStream_t stream) {
    const float* x       = (const float*)d_in[0];
    const int*   ei      = (const int*)d_in[1];   // [2][E]: src row 0, dst row 1
    const float* ew      = (const float*)d_in[2];
    const float* sub_fea = (const float*)d_in[3];
    const float* W1      = (const float*)d_in[4];
    const float* b1      = (const float*)d_in[5];
    const float* W2      = (const float*)d_in[6];
    const float* b2      = (const float*)d_in[7];
    const float* fc_w    = (const float*)d_in[8];
    const float* fc_b    = (const float*)d_in[9];
    float* out = (float*)d_out;

    // Workspace layout (bytes).
    char* base = (char*)d_ws;
    unsigned char* A = (unsigned char*)(base);                  // support fp8, 4.8 MB
    unsigned short* Bb = (unsigned short*)(base + 4800000);     // h1 bf16 (9.6MB) / h2 bf16 (6.4MB)
    float* pooled = (float*)(base + 14400512);                  // 64 f32
    int*   gcnt  = (int*)(base + 14401024);                     // 391 ints
    int*   off   = (int*)(base + 14403072);                     // 50001 ints
    unsigned* ewq = (unsigned*)(base + 14603264);               // 800000 u32 (3.2 MB)
    int2*  scratch = (int2*)(base + 17803264);                  // 391*4096 int2 (12.8 MB)
    unsigned short* Wt1 = (unsigned short*)(base + 30615552);   // 96*256 bf16
    unsigned short* Wt2 = (unsigned short*)(base + 30664704);   // 64*96 bf16

    const int* srcv = ei;
    const int* dstv = ei + N_EDGES;

    // ---- prep (weights + zero counters) ----
    prep_kernel<<<122, 256, 0, stream>>>(W1, W2, Wt1, Wt2, gcnt, pooled);

    // ---- mega1: bucket sort pass 1 || gemm1 (independent) ----
    mega1_kernel<<<NB_B1 + NB_GEMM1, 256, 0, stream>>>(srcv, dstv, ew, gcnt, scratch,
                                                       x, Wt1, A);

    // ---- bucket2: dst-sort within buckets, writes off + ewq ----
    bucket2_kernel<<<NBKT, 256, 0, stream>>>(scratch, gcnt, off, ewq);

    // ---- Layer 1 gather: h1 = bf16(relu(agg(fp8 support1) + b1)) ----
    {
        unsigned total = (unsigned)N_NODES * 24;
        gather_agg_kernel<96><<<(total + 255) / 256, 256, 0, stream>>>(
            A, off, ewq, b1, Bb);
    }

    // ---- Layer 2: support2 = fp8(h1 @ W2) ----
    gemm2_kernel<<<NB_GEMM1, 256, 0, stream>>>(Bb, Wt2, A);

    // ---- Layer 2 gather: h2 = bf16 relu(agg(fp8 support2) + b2) ----
    {
        unsigned total = (unsigned)N_NODES * 16;
        gather_agg_kernel<64><<<(total + 255) / 256, 256, 0, stream>>>(
            A, off, ewq, b2, Bb);
    }

    // ---- Pool + head ----
    colsum_kernel<<<(N_NODES + 255) / 256, 256, 0, stream>>>(Bb, pooled);
    final_kernel<<<1, 64, 0, stream>>>(pooled, sub_fea, fc_w, fc_b, out);
}